// Round 5
// baseline (165.736 us; speedup 1.0000x reference)
//
#include <hip/hip_runtime.h>
#include <stdint.h>

static constexpr int Kdim  = 1024;    // L
static constexpr int Ncols = 512;     // OUT

typedef __attribute__((ext_vector_type(8))) short bf16x8;
typedef __attribute__((ext_vector_type(4))) float f32x4;

union pk8 { uint4 u; bf16x8 h; };

__device__ __forceinline__ unsigned short f2bf(float f) {
  unsigned u = __builtin_bit_cast(unsigned, f);
  u += 0x7FFFu + ((u >> 16) & 1u);          // RNE
  return (unsigned short)(u >> 16);
}
__device__ __forceinline__ unsigned f2bf2(float lo, float hi) {
  unsigned ul = __builtin_bit_cast(unsigned, lo);
  unsigned uh = __builtin_bit_cast(unsigned, hi);
  ul += 0x7FFFu + ((ul >> 16) & 1u);
  uh += 0x7FFFu + ((uh >> 16) & 1u);
  return (ul >> 16) | (uh & 0xFFFF0000u);
}

// async global->LDS, 16B per lane; LDS dest = wave-uniform base + lane*16
__device__ __forceinline__ void gl2lds16(const void* g, void* l) {
  __builtin_amdgcn_global_load_lds(
      (const __attribute__((address_space(1))) void*)g,
      (__attribute__((address_space(3))) void*)l, 16, 0, 0);
}

// ---------------------------------------------------------------------------
// Kernel 1 (tiny): Wt[n][k] = bf16(0.5*(W_in[k][n]+W_out[k][n])+W_root[k][n])
// ---------------------------------------------------------------------------
__global__ __launch_bounds__(256) void combine_w(
    const float* __restrict__ Win, const float* __restrict__ Wout,
    const float* __restrict__ Wroot, unsigned short* __restrict__ Wt)
{
  __shared__ unsigned short lds[32 * 36];
  const int bid = blockIdx.x;
  const int tk0 = (bid & 31) * 32;
  const int tn0 = (bid >> 5) * 32;
  const int t = threadIdx.x;
  {
    const int k  = t >> 3;
    const int nq = (t & 7) * 4;
    const int gi = (tk0 + k) * Ncols + tn0 + nq;
    const float4 wi = *(const float4*)(Win + gi);
    const float4 wo = *(const float4*)(Wout + gi);
    const float4 wr = *(const float4*)(Wroot + gi);
    lds[(nq + 0) * 36 + k] = f2bf(0.5f * (wi.x + wo.x) + wr.x);
    lds[(nq + 1) * 36 + k] = f2bf(0.5f * (wi.y + wo.y) + wr.y);
    lds[(nq + 2) * 36 + k] = f2bf(0.5f * (wi.z + wo.z) + wr.z);
    lds[(nq + 3) * 36 + k] = f2bf(0.5f * (wi.w + wo.w) + wr.w);
  }
  __syncthreads();
  {
    const int n  = t >> 3;
    const int k8 = (t & 7) * 4;
    const ushort4 v = *(const ushort4*)&lds[n * 36 + k8];
    *(ushort4*)(Wt + (size_t)(tn0 + n) * Kdim + tk0 + k8) = v;
  }
}

// ---------------------------------------------------------------------------
// Kernel 2: Y = X(fp32) @ Wt^T + bias, FULL-N tiles: block = 64(M) x 512(N),
// grid 256 -> X is read from L3 exactly ONCE (the ~8 TB/s shared read path
// was the invariant ~58us bound in rounds 1/3/4). 512 thr = 8 waves, each a
// 64x64 wave-tile (4x4 mfma_f32_16x16x32_bf16, 64 acc VGPRs). B (1 MB Wt)
// streams from per-XCD L2 per K-slice. All staging via global_load_lds,
// double-buffered (2 x (8 KB A-fp32 + 32 KB B-bf16) = 80 KB LDS), ONE
// barrier/iter; A converted fp32->bf16 between ds_read and MFMA.
// Swizzles: A (128 B rows, 8 slots): slot = chunk ^ (row&7).
//           B (64 B rows, 4 slots): slot = chunk ^ ((row>>1)&3)  [round-3
//           scheme, measured 0 bank conflicts].
// ---------------------------------------------------------------------------
__global__ __launch_bounds__(512, 2) void gemm_fullN(
    const float* __restrict__ X, const unsigned short* __restrict__ Wt,
    const float* __restrict__ b_in, const float* __restrict__ b_out,
    const float* __restrict__ b_root, float* __restrict__ Y)
{
  __shared__ __attribute__((aligned(16))) float As[2][64 * 32];    // 2 x 8 KB
  __shared__ __attribute__((aligned(16))) short Bs[2][512 * 32];   // 2 x 32 KB

  const int m0 = blockIdx.x * 64;

  const int t    = threadIdx.x;
  const int lane = t & 63;
  const int w    = t >> 6;            // 0..7
  const int quad = lane >> 4;
  const int lm   = lane & 15;

  // --- A DMA: wave w stages A rows w*8..w*8+7 (one 1 KB inst)
  const int ra = lane >> 3;           // 0..7
  const int ca = (lane & 7) ^ ra;     // global chunk landing in slot lane&7
  const float* gA = X + (size_t)(m0 + w * 8 + ra) * Kdim + ca * 4;
  float* const lA = &As[0][0] + (w * 8) * 32;        // buf 0 float offset
  const int bufA = 64 * 32;                          // floats per A buffer

  // --- B DMA: wave w stages Wt rows w*64..w*64+63 (four 1 KB insts)
  const int rb = lane >> 2;           // 0..15
  const int cb = (lane & 3) ^ ((rb >> 1) & 3);
  const unsigned short* gB = Wt + (size_t)(w * 64 + rb) * Kdim + cb * 8;
  short* const lB = &Bs[0][0] + (w * 64) * 32;
  const int bufB = 512 * 32;                         // shorts per B buffer
  const int rowK16 = 16 * Kdim;

  // --- fragment offsets
  const int sA0   = (2 * quad) ^ (lm & 7);   // fp32 16B-slot of k=quad*8..+3
  const int slotB = quad ^ ((lm >> 1) & 3);
  const int aoff  = lm * 32;                          // + i*512 floats
  const int boff  = (w * 64 + lm) * 32 + slotB * 8;   // + j*512 shorts

  f32x4 acc[4][4] = {};

  // --- prologue: K-slice 0 -> buffer 0
  gl2lds16(gA, lA);
  #pragma unroll
  for (int g = 0; g < 4; ++g)
    gl2lds16(gB + (size_t)g * rowK16, lB + g * 512);

  #pragma unroll 1
  for (int it = 0; it < 32; ++it) {
    const int p = (it & 1);
    const int q = p ^ 1;
    __syncthreads();   // drains this wave's DMA -> buf[p] ready for all

    if (it != 31) {    // wave-uniform branch: issue next slice into buf[q]
      const int nx = (it + 1) * 32;
      gl2lds16(gA + nx, lA + q * bufA);
      #pragma unroll
      for (int g = 0; g < 4; ++g)
        gl2lds16(gB + nx + (size_t)g * rowK16, lB + q * bufB + g * 512);
    }

    const float* Ap = &As[0][0] + p * bufA;
    const short* Bp = &Bs[0][0] + p * bufB;

    bf16x8 bfr[4];
    #pragma unroll
    for (int j = 0; j < 4; ++j)
      bfr[j] = *(const bf16x8*)&Bp[boff + j * 512];

    bf16x8 af[4];
    #pragma unroll
    for (int i = 0; i < 4; ++i) {
      const f32x4 lo = *(const f32x4*)&Ap[i * 512 + aoff + sA0 * 4];
      const f32x4 hi = *(const f32x4*)&Ap[i * 512 + aoff + (sA0 ^ 1) * 4];
      pk8 pk;
      pk.u.x = f2bf2(lo.x, lo.y);
      pk.u.y = f2bf2(lo.z, lo.w);
      pk.u.z = f2bf2(hi.x, hi.y);
      pk.u.w = f2bf2(hi.z, hi.w);
      af[i] = pk.h;
    }

    #pragma unroll
    for (int i = 0; i < 4; ++i)
      #pragma unroll
      for (int j = 0; j < 4; ++j)
        acc[i][j] = __builtin_amdgcn_mfma_f32_16x16x32_bf16(af[i], bfr[j], acc[i][j], 0, 0, 0);
  }

  // epilogue: D[row=(lane>>4)*4+reg][col=lane&15] per 16x16 tile; bias fused
  #pragma unroll
  for (int j = 0; j < 4; ++j) {
    const int gc = w * 64 + j * 16 + lm;
    const float bias = 0.5f * (b_in[gc] + b_out[gc]) + b_root[gc];
    #pragma unroll
    for (int i = 0; i < 4; ++i) {
      const int gr = m0 + i * 16 + quad * 4;
      float* yp = Y + (size_t)gr * Ncols + gc;
      #pragma unroll
      for (int r = 0; r < 4; ++r)
        yp[(size_t)r * Ncols] = acc[i][j][r] + bias;
    }
  }
}

// ---------------------------------------------------------------------------
extern "C" void kernel_launch(void* const* d_in, const int* in_sizes, int n_in,
                              void* d_out, int out_size, void* d_ws, size_t ws_size,
                              hipStream_t stream)
{
  const float* x      = (const float*)d_in[0];
  // d_in[1] = At : dead input (ChebConv K=1 -> no neighbor aggregation)
  const float* W_in   = (const float*)d_in[2];
  const float* b_in   = (const float*)d_in[3];
  const float* W_out  = (const float*)d_in[4];
  const float* b_out  = (const float*)d_in[5];
  const float* W_root = (const float*)d_in[6];
  const float* b_root = (const float*)d_in[7];
  float* y = (float*)d_out;

  unsigned short* Wt = (unsigned short*)d_ws;   // 512*1024 bf16 = 1 MiB

  combine_w <<<dim3(512), dim3(256), 0, stream>>>(W_in, W_out, W_root, Wt);
  gemm_fullN<<<dim3(256), dim3(512), 0, stream>>>(x, Wt, b_in, b_out, b_root, y);
}